// Round 4
// baseline (162.801 us; speedup 1.0000x reference)
//
#include <hip/hip_runtime.h>
#include <math.h>

#define N_PTS 16384
#define D_DIM 128
#define C_CLS 10
#define K_MIX 16
#define GRID  440      // 10 classes x 44 blocks; <= 512 co-resident (2/CU)
#define BPC   44
#define HB    256      // 64-pt histogram / scatter chunks

constexpr float EPSF   = 1.1920928955078125e-07f;
constexpr float LOG2PI = 1.8378770664093453f;
constexpr float LN2F   = 0.6931471805599453f;

__device__ __forceinline__ float softplusf(float x) {
    if (x > 20.f)  return x;
    if (x < -20.f) return expf(x);
    return log1pf(expf(x));
}
__device__ __forceinline__ float ndtrf(float x) {
    return 0.5f * erfcf(-x * 0.70710678118654752440f);
}

// Device-scope grid barrier: per-barrier {cnt, flag} pair, zeroed by a
// captured hipMemsetAsync before each kernel launch (graph-replay safe).
__device__ __forceinline__ void gbar(int* cnt, int* flag) {
    __syncthreads();
    if (threadIdx.x == 0) {
        __threadfence();   // release: make my block's writes visible device-wide
        int prev = __hip_atomic_fetch_add(cnt, 1, __ATOMIC_ACQ_REL,
                                          __HIP_MEMORY_SCOPE_AGENT);
        if (prev == GRID - 1) {
            __hip_atomic_store(flag, 1, __ATOMIC_RELEASE,
                               __HIP_MEMORY_SCOPE_AGENT);
        } else {
            while (!__hip_atomic_load(flag, __ATOMIC_ACQUIRE,
                                      __HIP_MEMORY_SCOPE_AGENT))
                __builtin_amdgcn_s_sleep(8);
        }
        __threadfence();   // acquire: invalidate so I see others' writes
    }
    __syncthreads();
}

struct Args {
    const float* X; const int* y; const float* resp;
    const float* mu; const float* lower; const float* upper;
    const float* sigma; const float* logits; const float* eta;
    int* bar;                       // [0]=cnt1 [1]=flag1 [2]=cnt2 [3]=flag2 [4]=done
    float2* abT; float* loT; float* upT; float* Ack;
    float* const_ck; int* blockCnt; int* idxSorted; int* classOff;
    float* invden; float* partials; float* out;
};

__global__ __launch_bounds__(256, 2) void k_fused(Args a) {
    const int b = blockIdx.x, t = threadIdx.x;
    const int w = t >> 6, lane = t & 63;

    __shared__ int   sCnt[HB * C_CLS];     // 10 KiB
    __shared__ int   sOff[C_CLS + 1];
    __shared__ int   sMyOff[C_CLS];
    __shared__ float sLse[C_CLS];
    __shared__ float ws4[4];
    __shared__ int   sLast;

    // ---------------- P1: per-(c,k) params (waves u = 0..159) --------------
    {
        int u = b * 4 + w;
        if (u < C_CLS * K_MIX) {
            int c = u / K_MIX, k = u % K_MIX;
            float logsc = 0.f, mu2 = 0.f, zp = 1.f;
            #pragma unroll
            for (int h = 0; h < 2; ++h) {
                int d  = lane + 64 * h;
                int gi = u * D_DIM + d;
                float m = a.mu[gi], lo = a.lower[gi], up = a.upper[gi], sg = a.sigma[gi];
                float sc = EPSF + softplusf(sg);
                float is = 1.f / sc;
                int ti = (c * D_DIM + d) * K_MIX + k;
                a.abT[ti] = make_float2(is * is, 2.f * m * is * is);
                a.loT[ti] = lo; a.upT[ti] = up;
                logsc += logf(sc);
                mu2   += m * m * is * is;
                zp    *= ndtrf((up - m) * is) - ndtrf((lo - m) * is);
            }
            #pragma unroll
            for (int off = 1; off < 64; off <<= 1) {
                logsc += __shfl_xor(logsc, off);
                mu2   += __shfl_xor(mu2, off);
                zp    *= __shfl_xor(zp, off);
            }
            if (lane == 0)
                a.Ack[u] = -logf(zp + EPSF) - logsc
                         - 0.5f * (float)D_DIM * LOG2PI - 0.5f * mu2;
        }
        // P1b: per-64-pt class histogram (blocks 0..255, wave 0)
        if (b < HB && w == 0) {
            int c = a.y[b * 64 + lane];
            #pragma unroll
            for (int cc = 0; cc < C_CLS; ++cc) {
                unsigned long long m = __ballot(c == cc);
                if (lane == 0) a.blockCnt[b * C_CLS + cc] = __popcll(m);
            }
        }
    }
    gbar(&a.bar[0], &a.bar[1]);

    // ---------------- P2: deterministic counting-sort scatter + consts -----
    if (b < HB) {
        for (int i = t; i < HB * C_CLS; i += 256) sCnt[i] = a.blockCnt[i];
        __syncthreads();
        if (t < C_CLS) {
            int tot = 0;
            for (int h = 0; h < HB; ++h) tot += sCnt[h * C_CLS + t];
            sOff[t] = tot;                 // class totals (pre-scan)
        }
        __syncthreads();
        if (t == 0) {
            int acc = 0;
            for (int c = 0; c < C_CLS; ++c) { int v = sOff[c]; sOff[c] = acc; acc += v; }
            sOff[C_CLS] = acc;
        }
        __syncthreads();
        if (t < C_CLS) {
            int s = sOff[t];
            for (int h = 0; h < b; ++h) s += sCnt[h * C_CLS + t];
            sMyOff[t] = s;
        }
        __syncthreads();
        if (w == 0) {                      // stable scatter of this block's 64 pts
            int n = b * 64 + lane;
            int c = a.y[n];
            int rank = 0;
            #pragma unroll
            for (int cc = 0; cc < C_CLS; ++cc) {
                unsigned long long m = __ballot(c == cc);
                if (c == cc) rank = __popcll(m & ((1ull << lane) - 1ull));
            }
            a.idxSorted[sMyOff[c] + rank] = n;
        }
        if (b == 0) {
            if (t < C_CLS) {
                float mx = -1e30f;
                for (int k = 0; k < K_MIX; ++k) mx = fmaxf(mx, a.logits[t * K_MIX + k]);
                float se = 0.f;
                for (int k = 0; k < K_MIX; ++k) se += expf(a.logits[t * K_MIX + k] - mx);
                sLse[t] = mx + logf(se);
                int cnt = sOff[t + 1] - sOff[t];
                a.invden[t] = (cnt > 0) ? 1.f / ((float)cnt * (float)K_MIX) : 0.f;
            }
            if (t < C_CLS + 1) a.classOff[t] = sOff[t];
            __syncthreads();
            if (t < C_CLS * K_MIX)
                a.const_ck[t] = a.logits[t] - sLse[t / K_MIX] + a.Ack[t];
        }
    }
    gbar(&a.bar[2], &a.bar[3]);

    // ---------------- P3: main, class-uniform blocks, params in registers --
    {
        int c = b / BPC, j = b % BPC;
        int k = lane & 15, dc = lane >> 4;
        const int d0 = dc * 32;

        float a_[32], b_[32];
        const float2* ab = a.abT + (size_t)c * D_DIM * K_MIX + k;
        #pragma unroll
        for (int i = 0; i < 32; ++i) {
            float2 v = ab[(size_t)(d0 + i) * K_MIX];
            a_[i] = v.x; b_[i] = v.y;
        }
        float ck  = a.const_ck[c * K_MIX + k];
        float eta = a.eta[0];
        float inv = a.invden[c];
        int off = a.classOff[c];
        int cnt = a.classOff[c + 1] - off;
        const float lpconst = -2.f * (float)D_DIM * LN2F;

        float wsum = 0.f;
        for (int p = j * 4 + w; p < cnt; p += BPC * 4) {
            int n = a.idxSorted[off + p];
            const float* xr = a.X + (size_t)n * D_DIM + d0;
            float acc = 0.f, lp = lpconst;
            if (eta == 0.f) {
                #pragma unroll
                for (int i4 = 0; i4 < 8; ++i4) {
                    float4 xv = *reinterpret_cast<const float4*>(xr + i4 * 4);
                    acc = fmaf(xv.x, fmaf(a_[i4*4+0], xv.x, -b_[i4*4+0]), acc);
                    acc = fmaf(xv.y, fmaf(a_[i4*4+1], xv.y, -b_[i4*4+1]), acc);
                    acc = fmaf(xv.z, fmaf(a_[i4*4+2], xv.z, -b_[i4*4+2]), acc);
                    acc = fmaf(xv.w, fmaf(a_[i4*4+3], xv.w, -b_[i4*4+3]), acc);
                }
                acc += __shfl_xor(acc, 16);
                acc += __shfl_xor(acc, 32);
            } else {
                float lpp = 0.f;
                const float* lo = a.loT + (size_t)c * D_DIM * K_MIX + k;
                const float* up = a.upT + (size_t)c * D_DIM * K_MIX + k;
                #pragma unroll
                for (int i4 = 0; i4 < 8; ++i4) {
                    float4 xv = *reinterpret_cast<const float4*>(xr + i4 * 4);
                    float xs4[4] = {xv.x, xv.y, xv.z, xv.w};
                    #pragma unroll
                    for (int q = 0; q < 4; ++q) {
                        int i = i4 * 4 + q;
                        float x = xs4[q];
                        acc = fmaf(x, fmaf(a_[i], x, -b_[i]), acc);
                        float lov = lo[(size_t)(d0 + i) * K_MIX];
                        float upv = up[(size_t)(d0 + i) * K_MIX];
                        lpp -= softplusf(-eta * (x - lov)) + softplusf(-eta * (upv - x));
                    }
                }
                acc += __shfl_xor(acc, 16); acc += __shfl_xor(acc, 32);
                lpp += __shfl_xor(lpp, 16); lpp += __shfl_xor(lpp, 32);
                lp = lpp;
            }
            float r = a.resp[((size_t)c * N_PTS + n) * K_MIX + k];
            float v = r * (ck + lp - 0.5f * acc) * inv;
            v += __shfl_xor(v, 1); v += __shfl_xor(v, 2);
            v += __shfl_xor(v, 4); v += __shfl_xor(v, 8);
            wsum += v;
        }
        if (lane == 0) ws4[w] = wsum;
        __syncthreads();
        if (t == 0) {
            a.partials[b] = ws4[0] + ws4[1] + ws4[2] + ws4[3];
            __threadfence();
            int prev = __hip_atomic_fetch_add(&a.bar[4], 1, __ATOMIC_ACQ_REL,
                                              __HIP_MEMORY_SCOPE_AGENT);
            sLast = (prev == GRID - 1);
        }
        __syncthreads();
    }

    // ---------------- P4: last block reduces partials (fixed order) --------
    if (sLast) {
        __threadfence();   // acquire: see all partials
        __shared__ float red[256];
        float s = 0.f;
        for (int i = t; i < GRID; i += 256) s += a.partials[i];
        red[t] = s;
        __syncthreads();
        for (int off = 128; off > 0; off >>= 1) {
            if (t < off) red[t] += red[t + off];
            __syncthreads();
        }
        if (t == 0) a.out[0] = -red[0];
    }
}

// ---------------------------------------------------------------------------
extern "C" void kernel_launch(void* const* d_in, const int* in_sizes, int n_in,
                              void* d_out, int out_size, void* d_ws, size_t ws_size,
                              hipStream_t stream) {
    char* ws = (char*)d_ws;
    size_t off = 256;                    // first 256 B reserved for barrier vars
    auto alloc = [&](size_t bytes) {
        void* p = ws + off;
        off += (bytes + 255) & ~size_t(255);
        return p;
    };
    const size_t PE = (size_t)C_CLS * D_DIM * K_MIX;

    Args a;
    a.X      = (const float*)d_in[0];
    a.y      = (const int*)  d_in[1];
    a.resp   = (const float*)d_in[2];
    a.mu     = (const float*)d_in[3];
    a.lower  = (const float*)d_in[4];
    a.upper  = (const float*)d_in[5];
    a.sigma  = (const float*)d_in[6];
    a.logits = (const float*)d_in[7];
    a.eta    = (const float*)d_in[8];
    a.bar      = (int*)ws;
    a.abT      = (float2*)alloc(PE * sizeof(float2));
    a.loT      = (float*) alloc(PE * sizeof(float));
    a.upT      = (float*) alloc(PE * sizeof(float));
    a.Ack      = (float*) alloc(C_CLS * K_MIX * sizeof(float));
    a.const_ck = (float*) alloc(C_CLS * K_MIX * sizeof(float));
    a.blockCnt = (int*)   alloc(HB * C_CLS * sizeof(int));
    a.idxSorted= (int*)   alloc(N_PTS * sizeof(int));
    a.classOff = (int*)   alloc((C_CLS + 1) * sizeof(int));
    a.invden   = (float*) alloc(C_CLS * sizeof(float));
    a.partials = (float*) alloc(GRID * sizeof(float));
    a.out      = (float*)d_out;

    // zero the barrier counters/flags every launch (captured into the graph)
    hipMemsetAsync(ws, 0, 256, stream);
    k_fused<<<GRID, 256, 0, stream>>>(a);
}

// Round 5
// 48.315 us; speedup vs baseline: 3.3696x; 3.3696x over previous
//
#include <hip/hip_runtime.h>
#include <math.h>

#define N_PTS 16384
#define D_DIM 128
#define C_CLS 10
#define K_MIX 16
#define BPC   51                      // blocks per class
#define GRID  (C_CLS * BPC)           // 510 blocks, ~2/CU co-resident
#define NCHUNK (N_PTS / 64)           // 256 chunks of 64 points

constexpr float EPSF   = 1.1920928955078125e-07f;  // np.finfo(float32).eps
constexpr float LOG2PI = 1.8378770664093453f;
constexpr float LN2F   = 0.6931471805599453f;

__device__ __forceinline__ float softplusf(float x) {
    if (x > 20.f)  return x;
    if (x < -20.f) return expf(x);
    return log1pf(expf(x));
}
__device__ __forceinline__ float ndtrf(float x) {
    return 0.5f * erfcf(-x * 0.70710678118654752440f);
}

// ---------------------------------------------------------------------------
// K1: block = (class c, stripe j). Params (a=is^2, b=2*mu*is^2) computed into
// registers from raw mu/sigma. Waves ballot-scan y for matching points and
// process them. j==0 blocks additionally compute Ack[c][k] (split over waves).
// Outputs (all plain stores, no atomics):
//   partials1[b]      = sum_{n in stripe} sum_k resp*(lp - 0.5*acc)
//   partials2[b*16+k] = sum_{n in stripe} resp[n,k]
//   countB[b]         = #points matched in stripe
//   Ack[c*16+k]       (j==0 blocks only)
// ---------------------------------------------------------------------------
__global__ __launch_bounds__(256, 2) void k_main(
    const float* __restrict__ X, const int* __restrict__ y,
    const float* __restrict__ resp,
    const float* __restrict__ mu, const float* __restrict__ lower,
    const float* __restrict__ upper, const float* __restrict__ sigma,
    const float* __restrict__ etap,
    float* __restrict__ Ack, float* __restrict__ partials1,
    float* __restrict__ partials2, int* __restrict__ countB) {
    const int b = blockIdx.x, t = threadIdx.x;
    const int w = t >> 6, lane = t & 63;
    const int c = b / BPC, j = b % BPC;
    const int k = lane & 15, dc = lane >> 4;
    const int d0 = dc * 32;

    __shared__ float zW[4][16];
    __shared__ float sWsum[4];
    __shared__ float sRk[4][16];
    __shared__ int   sCntW[4];

    // ---- per-block param build: a_ = is^2, b_ = 2*mu*is^2 (regs) ----------
    const size_t pbase = ((size_t)(c * K_MIX + k)) * D_DIM + d0;
    float a_[32], b_[32];
    float logsc = 0.f, mu2 = 0.f;
    #pragma unroll
    for (int i4 = 0; i4 < 8; ++i4) {
        float4 mv = *reinterpret_cast<const float4*>(mu    + pbase + i4 * 4);
        float4 sv = *reinterpret_cast<const float4*>(sigma + pbase + i4 * 4);
        float m4[4] = {mv.x, mv.y, mv.z, mv.w};
        float s4[4] = {sv.x, sv.y, sv.z, sv.w};
        #pragma unroll
        for (int q = 0; q < 4; ++q) {
            int i = i4 * 4 + q;
            float sc = EPSF + softplusf(s4[q]);
            float is = 1.f / sc;
            a_[i] = is * is;
            b_[i] = 2.f * m4[q] * is * is;
            logsc += logf(sc);
            mu2   += m4[q] * m4[q] * is * is;
        }
    }

    // ---- j==0: compute Ack[c][k]; z-product split across the 4 waves ------
    if (j == 0) {
        float zp = 1.f;
        const size_t zbase = pbase + w * 8;   // this wave covers dims [w*8, w*8+8)
        #pragma unroll
        for (int i4 = 0; i4 < 2; ++i4) {
            float4 mv = *reinterpret_cast<const float4*>(mu    + zbase + i4 * 4);
            float4 sv = *reinterpret_cast<const float4*>(sigma + zbase + i4 * 4);
            float4 lv = *reinterpret_cast<const float4*>(lower + zbase + i4 * 4);
            float4 uv = *reinterpret_cast<const float4*>(upper + zbase + i4 * 4);
            float m4[4] = {mv.x, mv.y, mv.z, mv.w};
            float s4[4] = {sv.x, sv.y, sv.z, sv.w};
            float l4[4] = {lv.x, lv.y, lv.z, lv.w};
            float u4[4] = {uv.x, uv.y, uv.z, uv.w};
            #pragma unroll
            for (int q = 0; q < 4; ++q) {
                float sc = EPSF + softplusf(s4[q]);
                float is = 1.f / sc;
                zp *= ndtrf((u4[q] - m4[q]) * is) - ndtrf((l4[q] - m4[q]) * is);
            }
        }
        zp *= __shfl_xor(zp, 16);
        zp *= __shfl_xor(zp, 32);
        if (lane < 16) zW[w][lane] = zp;
    }
    // full-D sums for this lane's k (sum over dc groups)
    float logscF = logsc + 0.f, mu2F = mu2 + 0.f;
    logscF += __shfl_xor(logscF, 16); logscF += __shfl_xor(logscF, 32);
    mu2F   += __shfl_xor(mu2F, 16);   mu2F   += __shfl_xor(mu2F, 32);
    if (j == 0) {
        __syncthreads();
        if (w == 0 && lane < 16) {
            float zp = zW[0][lane] * zW[1][lane] * zW[2][lane] * zW[3][lane];
            Ack[c * K_MIX + lane] = -logf(zp + EPSF) - logscF
                                  - 0.5f * (float)D_DIM * LOG2PI - 0.5f * mu2F;
        }
    }

    // ---- main ballot-scan loop ---------------------------------------------
    const float eta = etap[0];
    const float lpconst = -2.f * (float)D_DIM * LN2F;
    float wsum = 0.f, rk = 0.f;
    int myCount = 0;

    for (int q = j * 4 + w; q < NCHUNK; q += BPC * 4) {
        int n0 = q * 64;
        int yv = y[n0 + lane];
        unsigned long long m = __ballot(yv == c);
        myCount += __popcll(m);
        while (m) {
            int s = __builtin_ctzll(m);
            m &= m - 1;
            int n = n0 + s;
            const float* xr = X + (size_t)n * D_DIM + d0;
            float acc = 0.f, lp = lpconst;
            #pragma unroll
            for (int i4 = 0; i4 < 8; ++i4) {
                float4 xv = *reinterpret_cast<const float4*>(xr + i4 * 4);
                acc = fmaf(xv.x, fmaf(a_[i4*4+0], xv.x, -b_[i4*4+0]), acc);
                acc = fmaf(xv.y, fmaf(a_[i4*4+1], xv.y, -b_[i4*4+1]), acc);
                acc = fmaf(xv.z, fmaf(a_[i4*4+2], xv.z, -b_[i4*4+2]), acc);
                acc = fmaf(xv.w, fmaf(a_[i4*4+3], xv.w, -b_[i4*4+3]), acc);
            }
            if (eta != 0.f) {
                float lpp = 0.f;
                #pragma unroll
                for (int i4 = 0; i4 < 8; ++i4) {
                    float4 xv = *reinterpret_cast<const float4*>(xr + i4 * 4);
                    float4 lv = *reinterpret_cast<const float4*>(lower + pbase + i4 * 4);
                    float4 uv = *reinterpret_cast<const float4*>(upper + pbase + i4 * 4);
                    float x4[4] = {xv.x, xv.y, xv.z, xv.w};
                    float l4[4] = {lv.x, lv.y, lv.z, lv.w};
                    float u4[4] = {uv.x, uv.y, uv.z, uv.w};
                    #pragma unroll
                    for (int qq = 0; qq < 4; ++qq)
                        lpp -= softplusf(-eta * (x4[qq] - l4[qq]))
                             + softplusf(-eta * (u4[qq] - x4[qq]));
                }
                lpp += __shfl_xor(lpp, 16);
                lpp += __shfl_xor(lpp, 32);
                lp = lpp;
            }
            acc += __shfl_xor(acc, 16);
            acc += __shfl_xor(acc, 32);
            float r = resp[((size_t)c * N_PTS + n) * K_MIX + k];
            rk += r;
            float v = r * fmaf(-0.5f, acc, lp);
            v += __shfl_xor(v, 1); v += __shfl_xor(v, 2);
            v += __shfl_xor(v, 4); v += __shfl_xor(v, 8);
            wsum += v;   // wave-uniform
        }
    }

    if (lane == 0) { sWsum[w] = wsum; sCntW[w] = myCount; }
    if (lane < 16) sRk[w][lane] = rk;
    __syncthreads();
    if (t == 0) {
        partials1[b] = sWsum[0] + sWsum[1] + sWsum[2] + sWsum[3];
        countB[b]    = sCntW[0] + sCntW[1] + sCntW[2] + sCntW[3];
    }
    if (t < K_MIX)
        partials2[b * K_MIX + t] = sRk[0][t] + sRk[1][t] + sRk[2][t] + sRk[3][t];
}

// ---------------------------------------------------------------------------
// K2: single block. Assemble loss in fixed order (deterministic).
// ---------------------------------------------------------------------------
__global__ __launch_bounds__(256) void k_final(
    const float* __restrict__ logits, const float* __restrict__ Ack,
    const float* __restrict__ partials1, const float* __restrict__ partials2,
    const int* __restrict__ countB, float* __restrict__ out) {
    __shared__ float sS1[C_CLS];
    __shared__ int   sCnt[C_CLS];
    __shared__ float sLse[C_CLS];
    __shared__ float sR[C_CLS * K_MIX];
    int t = threadIdx.x;
    if (t < C_CLS) {
        float s = 0.f; int cn = 0;
        for (int jj = 0; jj < BPC; ++jj) {
            s  += partials1[t * BPC + jj];
            cn += countB[t * BPC + jj];
        }
        sS1[t] = s; sCnt[t] = cn;
        float mx = -1e30f;
        for (int k = 0; k < K_MIX; ++k) mx = fmaxf(mx, logits[t * K_MIX + k]);
        float se = 0.f;
        for (int k = 0; k < K_MIX; ++k) se += expf(logits[t * K_MIX + k] - mx);
        sLse[t] = mx + logf(se);
    }
    if (t < C_CLS * K_MIX) {
        int c = t / K_MIX, k = t % K_MIX;
        float s = 0.f;
        for (int jj = 0; jj < BPC; ++jj)
            s += partials2[((size_t)(c * BPC + jj)) * K_MIX + k];
        sR[t] = s;
    }
    __syncthreads();
    if (t == 0) {
        float loss = 0.f;
        for (int c = 0; c < C_CLS; ++c) {
            float cs = sS1[c];
            for (int k = 0; k < K_MIX; ++k)
                cs += sR[c * K_MIX + k]
                    * (logits[c * K_MIX + k] - sLse[c] + Ack[c * K_MIX + k]);
            float den = (float)sCnt[c] * (float)K_MIX;
            if (sCnt[c] > 0) loss += cs / den;
        }
        out[0] = -loss;
    }
}

// ---------------------------------------------------------------------------
extern "C" void kernel_launch(void* const* d_in, const int* in_sizes, int n_in,
                              void* d_out, int out_size, void* d_ws, size_t ws_size,
                              hipStream_t stream) {
    const float* X      = (const float*)d_in[0];
    const int*   y      = (const int*)  d_in[1];
    const float* resp   = (const float*)d_in[2];
    const float* mu     = (const float*)d_in[3];
    const float* lower  = (const float*)d_in[4];
    const float* upper  = (const float*)d_in[5];
    const float* sigma  = (const float*)d_in[6];
    const float* logits = (const float*)d_in[7];
    const float* eta    = (const float*)d_in[8];
    float* out = (float*)d_out;

    char* ws = (char*)d_ws;
    size_t off = 0;
    auto alloc = [&](size_t bytes) {
        void* p = ws + off;
        off += (bytes + 255) & ~size_t(255);
        return p;
    };
    float* Ack       = (float*)alloc(C_CLS * K_MIX * sizeof(float));
    float* partials1 = (float*)alloc(GRID * sizeof(float));
    float* partials2 = (float*)alloc(GRID * K_MIX * sizeof(float));
    int*   countB    = (int*)  alloc(GRID * sizeof(int));

    k_main<<<GRID, 256, 0, stream>>>(X, y, resp, mu, lower, upper, sigma, eta,
                                     Ack, partials1, partials2, countB);
    k_final<<<1, 256, 0, stream>>>(logits, Ack, partials1, partials2, countB, out);
}

// Round 6
// 47.196 us; speedup vs baseline: 3.4495x; 1.0237x over previous
//
#include <hip/hip_runtime.h>
#include <math.h>

#define N_PTS 16384
#define D_DIM 128
#define C_CLS 10
#define K_MIX 16
#define HB    64                      // histogram/scatter blocks (256 pts each)
#define BPC   28                      // main blocks per class
#define GRID3 (C_CLS * BPC)           // 280 main blocks

constexpr float EPSF   = 1.1920928955078125e-07f;  // np.finfo(float32).eps
constexpr float LOG2PI = 1.8378770664093453f;
constexpr float LN2F   = 0.6931471805599453f;

__device__ __forceinline__ float softplusf(float x) {
    if (x > 20.f)  return x;
    if (x < -20.f) return expf(x);
    return log1pf(expf(x));
}
__device__ __forceinline__ float ndtrf(float x) {
    return 0.5f * erfcf(-x * 0.70710678118654752440f);
}

// ---------------------------------------------------------------------------
// K1: blocks [0,160): per-(c,k) params -> ab[c][k][d] (float2 {is^2, 2 mu is^2}),
//     loT/upT[c][k][d], Ack[c*K+k] (with -0.5*sum mu^2 is^2 folded).
//     blocks [160,224): per-256-pt class histogram -> blockCnt[h][c].
// (Round-2 proven structure; only the ab layout changed — now coalesced.)
// ---------------------------------------------------------------------------
__global__ __launch_bounds__(256) void k_prep(
    const float* __restrict__ mu, const float* __restrict__ lower,
    const float* __restrict__ upper, const float* __restrict__ sigma,
    const int* __restrict__ y,
    float2* __restrict__ ab, float* __restrict__ loT, float* __restrict__ upT,
    float* __restrict__ Ack, int* __restrict__ blockCnt) {
    int b = blockIdx.x, t = threadIdx.x;
    if (b < C_CLS * K_MIX) {
        __shared__ float rs0[256], rs1[256], rp[256];
        float logsc = 0.f, mu2 = 0.f, zz = 1.f;
        if (t < D_DIM) {
            int gi = b * D_DIM + t;
            float m = mu[gi], lo = lower[gi], up = upper[gi], sg = sigma[gi];
            float sc = EPSF + softplusf(sg);
            float is = 1.f / sc;
            ab[gi]  = make_float2(is * is, 2.f * m * is * is);
            loT[gi] = lo; upT[gi] = up;
            logsc = logf(sc);
            mu2   = m * m * is * is;
            zz    = ndtrf((up - m) * is) - ndtrf((lo - m) * is);
        }
        rs0[t] = logsc; rs1[t] = mu2; rp[t] = zz;
        __syncthreads();
        for (int off = 128; off > 0; off >>= 1) {
            if (t < off) { rs0[t] += rs0[t+off]; rs1[t] += rs1[t+off]; rp[t] *= rp[t+off]; }
            __syncthreads();
        }
        if (t == 0) {
            float log_norm = logf(rp[0] + EPSF);
            Ack[b] = -log_norm - rs0[0] - 0.5f * (float)D_DIM * LOG2PI - 0.5f * rs1[0];
        }
    } else {
        int h = b - C_CLS * K_MIX;
        __shared__ int hist[C_CLS];
        if (t < C_CLS) hist[t] = 0;
        __syncthreads();
        int c = y[h * 256 + t];
        int lane = t & 63;
        for (int cc = 0; cc < C_CLS; ++cc) {
            unsigned long long m = __ballot(c == cc);
            if (lane == 0 && m) atomicAdd(&hist[cc], __popcll(m));
        }
        __syncthreads();
        if (t < C_CLS) blockCnt[h * C_CLS + t] = hist[t];
    }
}

// ---------------------------------------------------------------------------
// K2: stable counting-sort scatter (deterministic) + const_ck/classOff/invden.
// (Round-2 proven, verbatim.)
// ---------------------------------------------------------------------------
__global__ __launch_bounds__(256) void k_scatter(
    const int* __restrict__ y, const int* __restrict__ blockCnt,
    const float* __restrict__ logits, const float* __restrict__ Ack,
    int* __restrict__ idxSorted, int* __restrict__ classOff,
    float* __restrict__ invden, float* __restrict__ const_ck) {
    __shared__ int sCnt[HB * C_CLS];
    __shared__ int sOff[C_CLS + 1];
    __shared__ int sMyOff[C_CLS];
    __shared__ int wcnt[4][C_CLS];
    __shared__ int wbase[4][C_CLS];
    int h = blockIdx.x, t = threadIdx.x;
    for (int i = t; i < HB * C_CLS; i += 256) sCnt[i] = blockCnt[i];
    __syncthreads();
    if (t == 0) {
        int acc = 0;
        for (int c = 0; c < C_CLS; ++c) {
            sOff[c] = acc;
            int s = 0;
            for (int hh = 0; hh < HB; ++hh) s += sCnt[hh * C_CLS + c];
            acc += s;
        }
        sOff[C_CLS] = acc;
    }
    __syncthreads();
    if (t < C_CLS) {
        int s = sOff[t];
        for (int hh = 0; hh < h; ++hh) s += sCnt[hh * C_CLS + t];
        sMyOff[t] = s;
    }
    __syncthreads();
    int n = h * 256 + t;
    int c = y[n];
    int w = t >> 6, lane = t & 63;
    int rank = 0;
    for (int cc = 0; cc < C_CLS; ++cc) {
        unsigned long long m = __ballot(c == cc);
        if (c == cc) rank = __popcll(m & ((1ull << lane) - 1ull));
        if (lane == 0) wcnt[w][cc] = __popcll(m);
    }
    __syncthreads();
    if (t < 4 * C_CLS) {
        int ww = t / C_CLS, cc = t % C_CLS;
        int s = sMyOff[cc];
        for (int w2 = 0; w2 < ww; ++w2) s += wcnt[w2][cc];
        wbase[ww][cc] = s;
    }
    __syncthreads();
    idxSorted[wbase[w][c] + rank] = n;

    if (h == 0) {
        __shared__ float lse[C_CLS];
        if (t < C_CLS) {
            float mx = -1e30f;
            for (int k = 0; k < K_MIX; ++k) mx = fmaxf(mx, logits[t * K_MIX + k]);
            float se = 0.f;
            for (int k = 0; k < K_MIX; ++k) se += expf(logits[t * K_MIX + k] - mx);
            lse[t] = mx + logf(se);
            int cnt = sOff[t + 1] - sOff[t];
            invden[t] = (cnt > 0) ? 1.f / ((float)cnt * (float)K_MIX) : 0.f;
        }
        if (t < C_CLS + 1) classOff[t] = sOff[t];
        __syncthreads();
        if (t < C_CLS * K_MIX) const_ck[t] = logits[t] - lse[t / K_MIX] + Ack[t];
    }
}

// ---------------------------------------------------------------------------
// K3: main. Block = (class c, stripe j); wave = 16 k-lanes x 4 dc-groups;
// params in registers; NO per-point shuffles (dc/k sums folded into wsum);
// dual-point unroll with all loads hoisted (MLP). Last block does the final
// fixed-order reduce (deterministic regardless of which block is last).
// ---------------------------------------------------------------------------
__global__ __launch_bounds__(256) void k_main(
    const float* __restrict__ X, const float* __restrict__ resp,
    const float2* __restrict__ ab, const float* __restrict__ loT,
    const float* __restrict__ upT, const float* __restrict__ const_ck,
    const int* __restrict__ classOff, const float* __restrict__ invden,
    const int* __restrict__ idxSorted, const float* __restrict__ etap,
    float* __restrict__ partials, int* __restrict__ done,
    float* __restrict__ out) {
    const int b = blockIdx.x, t = threadIdx.x;
    const int w = t >> 6, lane = t & 63;
    const int k = lane & 15, dc = lane >> 4;
    const int d0 = dc * 32;
    const int c = b / BPC, j = b % BPC;

    __shared__ float sW[4];
    __shared__ int   sLast;

    // params for this lane's (c,k), dims [d0, d0+32)
    float a_[32], b_[32];
    {
        const float2* p = ab + ((size_t)(c * K_MIX + k)) * D_DIM + d0;
        #pragma unroll
        for (int i = 0; i < 32; ++i) { float2 v = p[i]; a_[i] = v.x; b_[i] = v.y; }
    }
    const float eta = etap[0];
    const float lpconst = -2.f * (float)D_DIM * LN2F;
    const float ck4 = 0.25f * (const_ck[c * K_MIX + k] + (eta == 0.f ? lpconst : 0.f));
    const float inv = invden[c];
    const int off = classOff[c];
    const int cnt = classOff[c + 1] - off;

    float wsum = 0.f;
    if (eta == 0.f) {
        for (int base = j * 64; base < cnt; base += BPC * 64) {
            int rem = cnt - base; if (rem > 64) rem = 64;
            for (int i = w; i < rem; i += 8) {
                int i1 = i + 4;
                bool has1 = (i1 < rem);
                int n0 = idxSorted[off + base + i];
                int n1 = idxSorted[off + base + (has1 ? i1 : i)];
                const float4* x0 = reinterpret_cast<const float4*>(X + (size_t)n0 * D_DIM + d0);
                const float4* x1 = reinterpret_cast<const float4*>(X + (size_t)n1 * D_DIM + d0);
                float4 va[8], vb[8];
                #pragma unroll
                for (int q = 0; q < 8; ++q) va[q] = x0[q];
                #pragma unroll
                for (int q = 0; q < 8; ++q) vb[q] = x1[q];
                float r0 = resp[((size_t)c * N_PTS + n0) * K_MIX + k];
                float r1 = resp[((size_t)c * N_PTS + n1) * K_MIX + k];
                float acc0 = 0.f, acc1 = 0.f;
                #pragma unroll
                for (int q = 0; q < 8; ++q) {
                    acc0 = fmaf(va[q].x, fmaf(a_[q*4+0], va[q].x, -b_[q*4+0]), acc0);
                    acc0 = fmaf(va[q].y, fmaf(a_[q*4+1], va[q].y, -b_[q*4+1]), acc0);
                    acc0 = fmaf(va[q].z, fmaf(a_[q*4+2], va[q].z, -b_[q*4+2]), acc0);
                    acc0 = fmaf(va[q].w, fmaf(a_[q*4+3], va[q].w, -b_[q*4+3]), acc0);
                    acc1 = fmaf(vb[q].x, fmaf(a_[q*4+0], vb[q].x, -b_[q*4+0]), acc1);
                    acc1 = fmaf(vb[q].y, fmaf(a_[q*4+1], vb[q].y, -b_[q*4+1]), acc1);
                    acc1 = fmaf(vb[q].z, fmaf(a_[q*4+2], vb[q].z, -b_[q*4+2]), acc1);
                    acc1 = fmaf(vb[q].w, fmaf(a_[q*4+3], vb[q].w, -b_[q*4+3]), acc1);
                }
                float v0 = fmaf(-0.5f, acc0, ck4);
                wsum = fmaf(r0, v0, wsum);
                if (has1) {
                    float v1 = fmaf(-0.5f, acc1, ck4);
                    wsum = fmaf(r1, v1, wsum);
                }
            }
        }
    } else {
        const float4* lo4 = reinterpret_cast<const float4*>(loT + ((size_t)(c * K_MIX + k)) * D_DIM + d0);
        const float4* up4 = reinterpret_cast<const float4*>(upT + ((size_t)(c * K_MIX + k)) * D_DIM + d0);
        const float lpc4 = 0.25f * lpconst * 0.f; // lp computed fully below
        (void)lpc4;
        for (int base = j * 64; base < cnt; base += BPC * 64) {
            int rem = cnt - base; if (rem > 64) rem = 64;
            for (int i = w; i < rem; i += 4) {
                int n = idxSorted[off + base + i];
                const float4* xr = reinterpret_cast<const float4*>(X + (size_t)n * D_DIM + d0);
                float r = resp[((size_t)c * N_PTS + n) * K_MIX + k];
                float acc = 0.f, lpp = 0.f;
                #pragma unroll
                for (int q = 0; q < 8; ++q) {
                    float4 xv = xr[q];
                    float4 lv = lo4[q];
                    float4 uv = up4[q];
                    float x4[4] = {xv.x, xv.y, xv.z, xv.w};
                    float l4[4] = {lv.x, lv.y, lv.z, lv.w};
                    float u4[4] = {uv.x, uv.y, uv.z, uv.w};
                    #pragma unroll
                    for (int qq = 0; qq < 4; ++qq) {
                        float x = x4[qq];
                        acc = fmaf(x, fmaf(a_[q*4+qq], x, -b_[q*4+qq]), acc);
                        lpp -= softplusf(-eta * (x - l4[qq]))
                             + softplusf(-eta * (u4[qq] - x));
                    }
                }
                float v = fmaf(-0.5f, acc, ck4 + lpp);
                wsum = fmaf(r, v, wsum);
            }
        }
    }
    wsum *= inv;

    // one butterfly per wave (fixed order), then block combine
    #pragma unroll
    for (int o = 1; o < 64; o <<= 1) wsum += __shfl_xor(wsum, o);
    if (lane == 0) sW[w] = wsum;
    __syncthreads();
    if (t == 0) {
        partials[b] = sW[0] + sW[1] + sW[2] + sW[3];
        __threadfence();
        int prev = __hip_atomic_fetch_add(done, 1, __ATOMIC_ACQ_REL,
                                          __HIP_MEMORY_SCOPE_AGENT);
        sLast = (prev == GRID3 - 1);
    }
    __syncthreads();

    if (sLast) {
        __threadfence();
        __shared__ float red[256];
        float s = partials[t];
        if (t < GRID3 - 256) s += partials[256 + t];
        red[t] = s;
        __syncthreads();
        for (int o = 128; o > 0; o >>= 1) {
            if (t < o) red[t] += red[t + o];
            __syncthreads();
        }
        if (t == 0) out[0] = -red[0];
    }
}

// ---------------------------------------------------------------------------
extern "C" void kernel_launch(void* const* d_in, const int* in_sizes, int n_in,
                              void* d_out, int out_size, void* d_ws, size_t ws_size,
                              hipStream_t stream) {
    const float* X      = (const float*)d_in[0];
    const int*   y      = (const int*)  d_in[1];
    const float* resp   = (const float*)d_in[2];
    const float* mu     = (const float*)d_in[3];
    const float* lower  = (const float*)d_in[4];
    const float* upper  = (const float*)d_in[5];
    const float* sigma  = (const float*)d_in[6];
    const float* logits = (const float*)d_in[7];
    const float* eta    = (const float*)d_in[8];
    float* out = (float*)d_out;

    char* ws = (char*)d_ws;
    size_t off = 256;                 // first 256 B: done counter
    auto alloc = [&](size_t bytes) {
        void* p = ws + off;
        off += (bytes + 255) & ~size_t(255);
        return p;
    };
    const size_t PE = (size_t)C_CLS * K_MIX * D_DIM;
    int*    done     = (int*)ws;
    float2* ab       = (float2*)alloc(PE * sizeof(float2));
    float*  loT      = (float*) alloc(PE * sizeof(float));
    float*  upT      = (float*) alloc(PE * sizeof(float));
    float*  Ack      = (float*) alloc(C_CLS * K_MIX * sizeof(float));
    float*  const_ck = (float*) alloc(C_CLS * K_MIX * sizeof(float));
    int*    blockCnt = (int*)   alloc(HB * C_CLS * sizeof(int));
    int*    idxSorted= (int*)   alloc(N_PTS * sizeof(int));
    int*    classOff = (int*)   alloc((C_CLS + 1) * sizeof(int));
    float*  invden   = (float*) alloc(C_CLS * sizeof(float));
    float*  partials = (float*) alloc(GRID3 * sizeof(float));

    hipMemsetAsync(done, 0, sizeof(int), stream);
    k_prep<<<C_CLS * K_MIX + HB, 256, 0, stream>>>(
        mu, lower, upper, sigma, y, ab, loT, upT, Ack, blockCnt);
    k_scatter<<<HB, 256, 0, stream>>>(
        y, blockCnt, logits, Ack, idxSorted, classOff, invden, const_ck);
    k_main<<<GRID3, 256, 0, stream>>>(
        X, resp, ab, loT, upT, const_ck, classOff, invden, idxSorted, eta,
        partials, done, out);
}